// Round 6
// baseline (345.338 us; speedup 1.0000x reference)
//
#include <hip/hip_runtime.h>
#include <cstdint>

// ---------------------------------------------------------------------------
// T-LSTM cell, fp32 in/out, split-bf16 MFMA.
// Round 10: R9 (32x32x16 gates GEMM) with the LDS swizzle corrected.
// Bank model (fits all measurements R3-R9): wave64 ds_read_b128 is serviced
// as paired quads {4i..4i+3}U{32+4i..32+4i+3}; conflict-free iff the 8 bank
// quads are distinct. Old swizzle s(r)=(r>>1)&3 is conflict-free for the
// 16x16 pattern (chunks fq, fq^2 -> {s,s^1,s^2,s^3}) but 2-way for the
// 32x32 pattern (chunks q, q^1 -> {s,s^1} twice) -> R9's 1.26e7 conflicts.
// New swizzle s(r) = 3*((r>>1)&1): phys chunk = logical ^ s. Satisfies all
// four distinctness conditions for BOTH read patterns (derived, verified):
//   16x16 q in {0,2}: {0,3,2,1}  q in {1,3}: {1,2,3,0}
//   32x32 ks=0 {0,3,1,2}  ks=1 {2,1,3,0}
// Everything else identical to R9 (which passed -> layouts proven).
// ---------------------------------------------------------------------------

typedef __attribute__((ext_vector_type(8))) __bf16 bf16x8;
typedef __attribute__((ext_vector_type(4))) float f32x4;
typedef __attribute__((ext_vector_type(16))) float f32x16;

__device__ __forceinline__ unsigned short f2bf_rn(float f) {
  unsigned int u = __float_as_uint(f);
  unsigned int r = u + 0x7fffu + ((u >> 16) & 1u);
  return (unsigned short)(r >> 16);
}
__device__ __forceinline__ float bf2f(unsigned short h) {
  return __uint_as_float(((unsigned int)h) << 16);
}
__device__ __forceinline__ float sigm_f(float x) {
  return 1.0f / (1.0f + __expf(-x));
}
__device__ __forceinline__ float tanh_f(float x) {
  return 1.0f - 2.0f / (__expf(2.0f * x) + 1.0f);
}
__device__ __forceinline__ void gl_lds16(const void* g, void* l) {
  __builtin_amdgcn_global_load_lds(
      (const __attribute__((address_space(1))) void*)g,
      (__attribute__((address_space(3))) void*)l, 16, 0, 0);
}

// --- prep: split X=[input|hx], W=[w_ih|w_hh] (rows gate-interleaved), cx,
//           and transpose-split W_decomp, all in one dispatch.
__global__ __launch_bounds__(384) void prep_k(
    const float* __restrict__ input, const float* __restrict__ hx,
    const float* __restrict__ w_ih, const float* __restrict__ w_hh,
    const float* __restrict__ cx, const float* __restrict__ Wd,
    unsigned short* __restrict__ Xhi, unsigned short* __restrict__ Xlo,
    unsigned short* __restrict__ Whi, unsigned short* __restrict__ Wlo,
    unsigned short* __restrict__ Chi, unsigned short* __restrict__ Clo,
    unsigned short* __restrict__ Dhi, unsigned short* __restrict__ Dlo) {
  const int bid = blockIdx.x;
  if (bid >= 12288) {
    __shared__ float tile[64][65];
    const int tb = bid - 12288;
    const int bx = (tb & 15) * 64;
    const int by = (tb >> 4) * 64;
    const int tx = threadIdx.x & 63;
    const int ty = threadIdx.x >> 6;  // 0..5
    for (int r = ty; r < 64; r += 6)
      tile[r][tx] = Wd[(long)(by + r) * 1024 + bx + tx];
    __syncthreads();
    for (int r = ty; r < 64; r += 6) {
      float v = tile[tx][r];  // = Wd[by+tx][bx+r]
      unsigned short h = f2bf_rn(v);
      long o = (long)(bx + r) * 1024 + by + tx;
      Dhi[o] = h;
      Dlo[o] = f2bf_rn(v - bf2f(h));
    }
    return;
  }
  const int k = threadIdx.x << 2;
  const float* src;
  unsigned short *hi, *lo;
  if (bid < 4096) {
    const long m = bid;
    src = (k < 512) ? (input + m * 512 + k) : (hx + m * 1024 + (k - 512));
    hi = Xhi + m * 1536 + k;
    lo = Xlo + m * 1536 + k;
  } else if (bid < 8192) {
    const int n = bid - 4096;
    const int g = n >> 10;
    const int h = n & 1023;
    const long nd = ((long)(h >> 4) << 6) | (g << 4) | (h & 15);  // 16-h interleave
    src = (k < 512) ? (w_ih + (long)n * 512 + k) : (w_hh + (long)n * 1024 + (k - 512));
    hi = Whi + nd * 1536 + k;
    lo = Wlo + nd * 1536 + k;
  } else {
    if (k >= 1024) return;
    const long m = bid - 8192;
    src = cx + m * 1024 + k;
    hi = Chi + m * 1024 + k;
    lo = Clo + m * 1024 + k;
  }
  float4 v = *(const float4*)src;
  ushort4 hv, lv;
  hv.x = f2bf_rn(v.x); lv.x = f2bf_rn(v.x - bf2f(hv.x));
  hv.y = f2bf_rn(v.y); lv.y = f2bf_rn(v.y - bf2f(hv.y));
  hv.z = f2bf_rn(v.z); lv.z = f2bf_rn(v.z - bf2f(hv.z));
  hv.w = f2bf_rn(v.w); lv.w = f2bf_rn(v.w - bf2f(hv.w));
  *(ushort4*)hi = hv;
  *(ushort4*)lo = lv;
}

// --- mega kernel: per block (m_blk, n_blk):
//   phase 1: dacc[4] = cx[128m] @ D[32h]^T  (K=1024, 16x16x32 frags)
//   phase 2: acc[2][2] = X[128m] @ W'[128n']^T (K=1536, 32x32x16 frags)
//   epilogue: shuffle-exchange gates/dacc, full T-LSTM pointwise -> hy, cy
// 256 thr, 4 waves 2Mx2N, wave tile 64x64.
// LDS swizzle: phys chunk p of row r holds logical p ^ (3*((r>>1)&1)).
__global__ __launch_bounds__(256) void gemm_mega(
    const unsigned short* __restrict__ Xh, const unsigned short* __restrict__ Xl,
    const unsigned short* __restrict__ Wh, const unsigned short* __restrict__ Wl,
    const unsigned short* __restrict__ Ch, const unsigned short* __restrict__ Cl,
    const unsigned short* __restrict__ Dh, const unsigned short* __restrict__ Dl,
    const float* __restrict__ b_ih, const float* __restrict__ b_hh,
    const float* __restrict__ b_d, const float* __restrict__ cx,
    const float* __restrict__ t, float* __restrict__ out) {
  __shared__ __align__(16) unsigned short sAh[128 * 32];
  __shared__ __align__(16) unsigned short sAl[128 * 32];
  __shared__ __align__(16) unsigned short sBh[128 * 32];
  __shared__ __align__(16) unsigned short sBl[128 * 32];

  // natural order (R4-proven): XCD x serves n_blk in {x, x+8, x+16, x+24}
  // for ALL m -> its 4 W-panels (3.1 MB) stay L2-resident the whole kernel.
  const int n_blk = blockIdx.x & 31;
  const int m_blk = blockIdx.x >> 5;
  const int m0 = m_blk * 128;
  const int n0 = n_blk * 128;  // interleaved-W row offset
  const int h0 = n_blk * 32;   // global h offset of this block

  const int tid = threadIdx.x;
  const int wave = tid >> 6;
  const int lane = tid & 63;
  const int wr = wave >> 1;   // 0..1 (M)
  const int wc = wave & 1;    // 0..1 (N)
  const int srow = lane >> 2;
  // staging fetch: logical chunk = (L&3) ^ s(srow), s(r)=3*((r>>1)&1)
  const int ssw = (((lane & 3) ^ (3 * ((lane >> 3) & 1))) << 3);  // bf16 elems
  const int fm = lane & 15;
  const int fq = lane >> 4;
  // 16x16 read: phys chunk = fq ^ s(row), row = base+fm
  const int psw = ((fq ^ (3 * ((fm >> 1) & 1))) << 3);
  const int col = lane & 31;   // 32x32 frag column
  const int hi5 = lane >> 5;   // 32x32 k-half

  // constant LDS staging destinations (per wave)
  unsigned short* const dA0h = sAh + (wave * 16) * 32;
  unsigned short* const dA0l = sAl + (wave * 16) * 32;
  unsigned short* const dA1h = sAh + (64 + wave * 16) * 32;
  unsigned short* const dA1l = sAl + (64 + wave * 16) * 32;
  unsigned short* const dB0h = sBh + (wave * 16) * 32;
  unsigned short* const dB0l = sBl + (wave * 16) * 32;
  unsigned short* const dB1h = sBh + (64 + wave * 16) * 32;
  unsigned short* const dB1l = sBl + (64 + wave * 16) * 32;

  // ---------------- phase 1: decomp  dacc = cx @ D^T (16x16) ----------------
  f32x4 dacc[4];
#pragma unroll
  for (int i = 0; i < 4; ++i) dacc[i] = {0.f, 0.f, 0.f, 0.f};

  {
    const long aoff = (long)(m0 + wave * 16 + srow) * 1024 + ssw;
    const unsigned short* pAh0 = Ch + aoff;
    const unsigned short* pAl0 = Cl + aoff;
    const unsigned short* pAh1 = pAh0 + 64 * 1024;
    const unsigned short* pAl1 = pAl0 + 64 * 1024;
    const unsigned short* pD =
        ((wave & 2) ? Dl : Dh) + (long)(h0 + (wave & 1) * 16 + srow) * 1024 + ssw;
    unsigned short* const dD = ((wave & 2) ? sBl : sBh) + ((wave & 1) * 16) * 32;

    for (int kt = 0; kt < 1024; kt += 128) {
#pragma unroll
      for (int kk = 0; kk < 4; ++kk) {
        gl_lds16(pAh0 + kk * 32, dA0h);
        gl_lds16(pAl0 + kk * 32, dA0l);
        gl_lds16(pAh1 + kk * 32, dA1h);
        gl_lds16(pAl1 + kk * 32, dA1l);
        gl_lds16(pD + kk * 32, dD);
        __syncthreads();
        bf16x8 ah[4], al[4];
#pragma unroll
        for (int mf = 0; mf < 4; ++mf) {
          const int ao = (wr * 64 + mf * 16 + fm) * 32 + psw;
          ah[mf] = *(const bf16x8*)(sAh + ao);
          al[mf] = *(const bf16x8*)(sAl + ao);
        }
        const int bo = (wc * 16 + fm) * 32 + psw;
        const bf16x8 bh = *(const bf16x8*)(sBh + bo);
        const bf16x8 bl = *(const bf16x8*)(sBl + bo);
#pragma unroll
        for (int mf = 0; mf < 4; ++mf) {
          dacc[mf] = __builtin_amdgcn_mfma_f32_16x16x32_bf16(ah[mf], bh, dacc[mf], 0, 0, 0);
          dacc[mf] = __builtin_amdgcn_mfma_f32_16x16x32_bf16(ah[mf], bl, dacc[mf], 0, 0, 0);
          dacc[mf] = __builtin_amdgcn_mfma_f32_16x16x32_bf16(al[mf], bh, dacc[mf], 0, 0, 0);
        }
        __syncthreads();
      }
      pAh0 += 128; pAl0 += 128; pAh1 += 128; pAl1 += 128; pD += 128;
    }
  }

  // ---------------- phase 2: gates  acc = X @ W'^T (32x32) ----------------
  f32x16 acc[2][2];
#pragma unroll
  for (int i = 0; i < 2; ++i)
#pragma unroll
    for (int j = 0; j < 2; ++j)
#pragma unroll
      for (int e = 0; e < 16; ++e) acc[i][j][e] = 0.f;

  // hoisted swizzled LDS read offsets: logical chunk q = hi5+2ks,
  // phys = q ^ s(row), s(r) = 3*((r>>1)&1)
  int offA[2][2], offB[2][2];
#pragma unroll
  for (int mf = 0; mf < 2; ++mf) {
    const int arow = wr * 64 + mf * 32 + col;
    const int s = 3 * ((arow >> 1) & 1);
#pragma unroll
    for (int ks = 0; ks < 2; ++ks)
      offA[mf][ks] = arow * 32 + (((hi5 + 2 * ks) ^ s) << 3);
  }
#pragma unroll
  for (int nf = 0; nf < 2; ++nf) {
    const int brow = wc * 64 + nf * 32 + col;
    const int s = 3 * ((brow >> 1) & 1);
#pragma unroll
    for (int ks = 0; ks < 2; ++ks)
      offB[nf][ks] = brow * 32 + (((hi5 + 2 * ks) ^ s) << 3);
  }

  {
    const long aoff = (long)(m0 + wave * 16 + srow) * 1536 + ssw;
    const long boff = (long)(n0 + wave * 16 + srow) * 1536 + ssw;
    const unsigned short* pXh0 = Xh + aoff;
    const unsigned short* pXl0 = Xl + aoff;
    const unsigned short* pXh1 = pXh0 + 64 * 1536;
    const unsigned short* pXl1 = pXl0 + 64 * 1536;
    const unsigned short* pWh0 = Wh + boff;
    const unsigned short* pWl0 = Wl + boff;
    const unsigned short* pWh1 = pWh0 + 64 * 1536;
    const unsigned short* pWl1 = pWl0 + 64 * 1536;

    for (int kt = 0; kt < 1536; kt += 128) {
#pragma unroll
      for (int kk = 0; kk < 4; ++kk) {
        gl_lds16(pXh0 + kk * 32, dA0h);
        gl_lds16(pXl0 + kk * 32, dA0l);
        gl_lds16(pXh1 + kk * 32, dA1h);
        gl_lds16(pXl1 + kk * 32, dA1l);
        gl_lds16(pWh0 + kk * 32, dB0h);
        gl_lds16(pWl0 + kk * 32, dB0l);
        gl_lds16(pWh1 + kk * 32, dB1h);
        gl_lds16(pWl1 + kk * 32, dB1l);
        __syncthreads();
        bf16x8 ah[2][2], al[2][2], bh[2][2], bl[2][2];
#pragma unroll
        for (int mf = 0; mf < 2; ++mf)
#pragma unroll
          for (int ks = 0; ks < 2; ++ks) {
            ah[mf][ks] = *(const bf16x8*)(sAh + offA[mf][ks]);
            al[mf][ks] = *(const bf16x8*)(sAl + offA[mf][ks]);
          }
#pragma unroll
        for (int nf = 0; nf < 2; ++nf)
#pragma unroll
          for (int ks = 0; ks < 2; ++ks) {
            bh[nf][ks] = *(const bf16x8*)(sBh + offB[nf][ks]);
            bl[nf][ks] = *(const bf16x8*)(sBl + offB[nf][ks]);
          }
#pragma unroll
        for (int ks = 0; ks < 2; ++ks)
#pragma unroll
          for (int nf = 0; nf < 2; ++nf)
#pragma unroll
            for (int mf = 0; mf < 2; ++mf) {
              acc[mf][nf] = __builtin_amdgcn_mfma_f32_32x32x16_bf16(
                  ah[mf][ks], bh[nf][ks], acc[mf][nf], 0, 0, 0);
              acc[mf][nf] = __builtin_amdgcn_mfma_f32_32x32x16_bf16(
                  ah[mf][ks], bl[nf][ks], acc[mf][nf], 0, 0, 0);
              acc[mf][nf] = __builtin_amdgcn_mfma_f32_32x32x16_bf16(
                  al[mf][ks], bh[nf][ks], acc[mf][nf], 0, 0, 0);
            }
        __syncthreads();
      }
      pXh0 += 128; pXl0 += 128; pXh1 += 128; pXl1 += 128;
      pWh0 += 128; pWl0 += 128; pWh1 += 128; pWl1 += 128;
    }
  }

  // ---------------- epilogue: shuffle-exchange + T-LSTM pointwise ----------
  // 32x32 C layout: col=lane&31, row=(reg&3)+8*(reg>>2)+4*(lane>>5).
  // n'_local = nf*32+col -> gate = 2*nf + b4, h_low = col&15.
  // Thread outputs half mf=b4 (rows b4*32+rowf); partner l^16 supplies the
  // other two gates for those rows; dacc (16x16 layout) gathered via shfl.
  const int b4 = (lane >> 4) & 1;
  const int hlow = lane & 15;
  const int h = h0 + wc * 16 + hlow;
  const float bi  = b_ih[h]        + b_hh[h];
  const float bff = b_ih[1024 + h] + b_hh[1024 + h];
  const float bg  = b_ih[2048 + h] + b_hh[2048 + h];
  const float bo2 = b_ih[3072 + h] + b_hh[3072 + h];
  const float bd  = b_d[h];
#pragma unroll
  for (int reg = 0; reg < 16; ++reg) {
    // send my acc of the half the partner outputs; receive partner's of mine
    const float s0 = b4 ? acc[0][0][reg] : acc[1][0][reg];
    const float s1 = b4 ? acc[0][1][reg] : acc[1][1][reg];
    const float r0 = __shfl_xor(s0, 16, 64);
    const float r1 = __shfl_xor(s1, 16, 64);
    const float a0 = b4 ? acc[1][0][reg] : acc[0][0][reg];  // own: gate b4
    const float a1 = b4 ? acc[1][1][reg] : acc[0][1][reg];  // own: gate 2+b4
    const float gi = b4 ? r0 : a0;
    const float gf = b4 ? a0 : r0;
    const float gg = b4 ? r1 : a1;
    const float go = b4 ? a1 : r1;
    // dacc gather: target row m_rel = b4*32 + (reg&3)+8*(reg>>2)+4*hi5
    const int lsrc = (((((reg >> 2) & 1) << 1) + hi5) << 4) | hlow;
    const float d0 = __shfl(dacc[(reg >> 3)][reg & 3], lsrc, 64);
    const float d1 = __shfl(dacc[2 + (reg >> 3)][reg & 3], lsrc, 64);
    const float dv = b4 ? d1 : d0;

    const int m = m0 + wr * 64 + b4 * 32 + (reg & 3) + 8 * (reg >> 2) + 4 * hi5;
    const float tv = t[m];
    const float T = (tv != 0.0f) ? (1.0f / tv) : 0.0f;
    const float cst = tanh_f(dv + bd);
    const float cadj = cx[(long)m * 1024 + h] + (T - 1.0f) * cst;
    const float ig = sigm_f(gi + bi);
    const float fg = sigm_f(gf + bff);
    const float cg = tanh_f(gg + bg);
    const float og = sigm_f(go + bo2);
    const float cyv = fg * cadj + ig * cg;
    const float hyv = og * tanh_f(cyv);
    out[(long)m * 1024 + h] = hyv;
    out[4096L * 1024 + (long)m * 1024 + h] = cyv;
  }
}

extern "C" void kernel_launch(void* const* d_in, const int* in_sizes, int n_in,
                              void* d_out, int out_size, void* d_ws, size_t ws_size,
                              hipStream_t stream) {
  const float* input = (const float*)d_in[0];
  const float* t     = (const float*)d_in[1];
  const float* hx    = (const float*)d_in[2];
  const float* cx    = (const float*)d_in[3];
  const float* w_ih  = (const float*)d_in[4];
  const float* w_hh  = (const float*)d_in[5];
  const float* b_ih  = (const float*)d_in[6];
  const float* b_hh  = (const float*)d_in[7];
  const float* Wd    = (const float*)d_in[8];
  const float* b_d   = (const float*)d_in[9];

  const long B = 4096, H = 1024, KX = 1536, NG = 4096;

  char* ws = (char*)d_ws;
  unsigned short* Xhi = (unsigned short*)ws; ws += B * KX * 2;
  unsigned short* Xlo = (unsigned short*)ws; ws += B * KX * 2;
  unsigned short* Whi = (unsigned short*)ws; ws += NG * KX * 2;
  unsigned short* Wlo = (unsigned short*)ws; ws += NG * KX * 2;
  unsigned short* Chi = (unsigned short*)ws; ws += B * H * 2;
  unsigned short* Clo = (unsigned short*)ws; ws += B * H * 2;
  unsigned short* Dhi = (unsigned short*)ws; ws += H * H * 2;
  unsigned short* Dlo = (unsigned short*)ws; ws += H * H * 2;

  // 1: hi/lo splits (X, W 16-h gate-interleaved, cx) + W_decomp transpose
  prep_k<<<12544, 384, 0, stream>>>(input, hx, w_ih, w_hh, cx, Wd,
                                    Xhi, Xlo, Whi, Wlo, Chi, Clo, Dhi, Dlo);
  // 2: mega GEMM (decomp 16x16 + gates 32x32 + shuffle epilogue)
  gemm_mega<<<1024, 256, 0, stream>>>(Xhi, Xlo, Whi, Wlo, Chi, Clo, Dhi, Dlo,
                                      b_ih, b_hh, b_d, cx, t, (float*)d_out);
}

// Round 7
// 321.913 us; speedup vs baseline: 1.0728x; 1.0728x over previous
//
#include <hip/hip_runtime.h>
#include <cstdint>

// ---------------------------------------------------------------------------
// T-LSTM cell, fp32 in/out, split-bf16 MFMA.
// Round 11: revert gemm_mega to the R8 optimum (measured 215.9us, 0 LDS bank
// conflicts, FETCH 201MB). R9/R10's 32x32 experiments both regressed on
// SQ_LDS_BANK_CONFLICT (1.26e7 / 4.30e7) -> bank model unresolved, reverted.
// Proven components kept: 128x128 block, 4 waves 2Mx2N (64x64/wave), nf==gate
// via 16-h interleave, single-buffered 32KB LDS (4 blocks/CU -> block-level
// desync provides the pipeline overlap), natural bid order (XCD keeps its 4
// W-panels L2-resident), pointer-walk staging, chunk-XOR swizzle
// s(r)=(r>>1)&3 (0 conflicts for the 16x16 read pattern, R3-R8 verified).
// Prep-only change: cx-split fused into X-split blocks (grid 12544 -> 8448).
// ---------------------------------------------------------------------------

typedef __attribute__((ext_vector_type(8))) __bf16 bf16x8;
typedef __attribute__((ext_vector_type(4))) float f32x4;

__device__ __forceinline__ unsigned short f2bf_rn(float f) {
  unsigned int u = __float_as_uint(f);
  unsigned int r = u + 0x7fffu + ((u >> 16) & 1u);
  return (unsigned short)(r >> 16);
}
__device__ __forceinline__ float bf2f(unsigned short h) {
  return __uint_as_float(((unsigned int)h) << 16);
}
__device__ __forceinline__ float sigm_f(float x) {
  return 1.0f / (1.0f + __expf(-x));
}
__device__ __forceinline__ float tanh_f(float x) {
  return 1.0f - 2.0f / (__expf(2.0f * x) + 1.0f);
}
__device__ __forceinline__ void gl_lds16(const void* g, void* l) {
  __builtin_amdgcn_global_load_lds(
      (const __attribute__((address_space(1))) void*)g,
      (__attribute__((address_space(3))) void*)l, 16, 0, 0);
}

// --- prep: split X=[input|hx] + cx (fused), W=[w_ih|w_hh] (gate-interleaved),
//           and transpose-split W_decomp, all in one dispatch.
// blocks [0,4096): X row m (384 thr x 4) AND cx row m (256 thr x 4)
// blocks [4096,8192): W source row n -> dest row (h>>4)*64+g*16+(h&15)
// blocks [8192,8448): W_decomp 64x64 transpose tiles (384 thr, stride-6 rows)
__global__ __launch_bounds__(384) void prep_k(
    const float* __restrict__ input, const float* __restrict__ hx,
    const float* __restrict__ w_ih, const float* __restrict__ w_hh,
    const float* __restrict__ cx, const float* __restrict__ Wd,
    unsigned short* __restrict__ Xhi, unsigned short* __restrict__ Xlo,
    unsigned short* __restrict__ Whi, unsigned short* __restrict__ Wlo,
    unsigned short* __restrict__ Chi, unsigned short* __restrict__ Clo,
    unsigned short* __restrict__ Dhi, unsigned short* __restrict__ Dlo) {
  const int bid = blockIdx.x;
  const int k = threadIdx.x << 2;
  if (bid >= 8192) {
    // ---- transpose-split W_decomp [1024,1024] -> D[h][kk] = Wd[kk][h]
    __shared__ float tile[64][65];
    const int tb = bid - 8192;
    const int bx = (tb & 15) * 64;
    const int by = (tb >> 4) * 64;
    const int tx = threadIdx.x & 63;
    const int ty = threadIdx.x >> 6;  // 0..5
    for (int r = ty; r < 64; r += 6)
      tile[r][tx] = Wd[(long)(by + r) * 1024 + bx + tx];
    __syncthreads();
    for (int r = ty; r < 64; r += 6) {
      float v = tile[tx][r];  // = Wd[by+tx][bx+r]
      unsigned short h = f2bf_rn(v);
      long o = (long)(bx + r) * 1024 + by + tx;
      Dhi[o] = h;
      Dlo[o] = f2bf_rn(v - bf2f(h));
    }
    return;
  }
  const float* src;
  unsigned short *hi, *lo;
  if (bid < 4096) {
    const long m = bid;
    // part 1: X = [input | hx]
    src = (k < 512) ? (input + m * 512 + k) : (hx + m * 1024 + (k - 512));
    hi = Xhi + m * 1536 + k;
    lo = Xlo + m * 1536 + k;
    {
      float4 v = *(const float4*)src;
      ushort4 hv, lv;
      hv.x = f2bf_rn(v.x); lv.x = f2bf_rn(v.x - bf2f(hv.x));
      hv.y = f2bf_rn(v.y); lv.y = f2bf_rn(v.y - bf2f(hv.y));
      hv.z = f2bf_rn(v.z); lv.z = f2bf_rn(v.z - bf2f(hv.z));
      hv.w = f2bf_rn(v.w); lv.w = f2bf_rn(v.w - bf2f(hv.w));
      *(ushort4*)hi = hv;
      *(ushort4*)lo = lv;
    }
    // part 2: cx (first 256 threads)
    if (k >= 1024) return;
    src = cx + m * 1024 + k;
    hi = Chi + m * 1024 + k;
    lo = Clo + m * 1024 + k;
  } else {
    const int n = bid - 4096;
    const int g = n >> 10;
    const int h = n & 1023;
    const long nd = ((long)(h >> 4) << 6) | (g << 4) | (h & 15);  // 16-h interleave
    src = (k < 512) ? (w_ih + (long)n * 512 + k) : (w_hh + (long)n * 1024 + (k - 512));
    hi = Whi + nd * 1536 + k;
    lo = Wlo + nd * 1536 + k;
  }
  float4 v = *(const float4*)src;
  ushort4 hv, lv;
  hv.x = f2bf_rn(v.x); lv.x = f2bf_rn(v.x - bf2f(hv.x));
  hv.y = f2bf_rn(v.y); lv.y = f2bf_rn(v.y - bf2f(hv.y));
  hv.z = f2bf_rn(v.z); lv.z = f2bf_rn(v.z - bf2f(hv.z));
  hv.w = f2bf_rn(v.w); lv.w = f2bf_rn(v.w - bf2f(hv.w));
  *(ushort4*)hi = hv;
  *(ushort4*)lo = lv;
}

// --- mega kernel (R8-identical): per block (m_blk, n_blk):
//   phase 1: dacc[4] = cx[128m] @ D[32h]^T  (K=1024)
//   phase 2: acc[4][4] = X[128m] @ W'[128n']^T (K=1536); nf == gate
//   epilogue: full T-LSTM pointwise -> hy, cy (direct to out)
// 256 thr, 4 waves 2Mx2N, wave tile 64x64 (4x4 16x16 frags).
// LDS swizzle (R3-verified, 0 conflicts): phys chunk p of row r holds logical
// chunk p^((r>>1)&3); staging lane L fetches logical (L&3)^((L>>3)&3).
__global__ __launch_bounds__(256) void gemm_mega(
    const unsigned short* __restrict__ Xh, const unsigned short* __restrict__ Xl,
    const unsigned short* __restrict__ Wh, const unsigned short* __restrict__ Wl,
    const unsigned short* __restrict__ Ch, const unsigned short* __restrict__ Cl,
    const unsigned short* __restrict__ Dh, const unsigned short* __restrict__ Dl,
    const float* __restrict__ b_ih, const float* __restrict__ b_hh,
    const float* __restrict__ b_d, const float* __restrict__ cx,
    const float* __restrict__ t, float* __restrict__ out) {
  __shared__ __align__(16) unsigned short sAh[128 * 32];
  __shared__ __align__(16) unsigned short sAl[128 * 32];
  __shared__ __align__(16) unsigned short sBh[128 * 32];
  __shared__ __align__(16) unsigned short sBl[128 * 32];

  // natural order (R4-proven): XCD x serves n_blk in {x, x+8, x+16, x+24}
  // for ALL m -> its 4 W-panels (3.1 MB) stay L2-resident the whole kernel.
  const int n_blk = blockIdx.x & 31;
  const int m_blk = blockIdx.x >> 5;
  const int m0 = m_blk * 128;
  const int n0 = n_blk * 128;  // interleaved-W row offset
  const int h0 = n_blk * 32;   // global h offset of this block

  const int tid = threadIdx.x;
  const int wave = tid >> 6;
  const int lane = tid & 63;
  const int wr = wave >> 1;   // 0..1 (M)
  const int wc = wave & 1;    // 0..1 (N)
  const int srow = lane >> 2;
  const int ssw = (((lane & 3) ^ ((lane >> 3) & 3)) << 3);  // bf16 elems
  const int fm = lane & 15;
  const int fq = lane >> 4;
  const int psw = (fq ^ ((fm >> 1) & 3)) << 3;

  // constant LDS staging destinations (per wave)
  unsigned short* const dA0h = sAh + (wave * 16) * 32;
  unsigned short* const dA0l = sAl + (wave * 16) * 32;
  unsigned short* const dA1h = sAh + (64 + wave * 16) * 32;
  unsigned short* const dA1l = sAl + (64 + wave * 16) * 32;
  unsigned short* const dB0h = sBh + (wave * 16) * 32;
  unsigned short* const dB0l = sBl + (wave * 16) * 32;
  unsigned short* const dB1h = sBh + (64 + wave * 16) * 32;
  unsigned short* const dB1l = sBl + (64 + wave * 16) * 32;

  // ---------------- phase 1: decomp  dacc = cx @ D^T ----------------
  f32x4 dacc[4];
#pragma unroll
  for (int i = 0; i < 4; ++i) dacc[i] = {0.f, 0.f, 0.f, 0.f};

  {
    const long aoff = (long)(m0 + wave * 16 + srow) * 1024 + ssw;
    const unsigned short* pAh0 = Ch + aoff;
    const unsigned short* pAl0 = Cl + aoff;
    const unsigned short* pAh1 = pAh0 + 64 * 1024;
    const unsigned short* pAl1 = pAl0 + 64 * 1024;
    const unsigned short* pD =
        ((wave & 2) ? Dl : Dh) + (long)(h0 + (wave & 1) * 16 + srow) * 1024 + ssw;
    unsigned short* const dD = ((wave & 2) ? sBl : sBh) + ((wave & 1) * 16) * 32;

    for (int kt = 0; kt < 1024; kt += 128) {
#pragma unroll
      for (int kk = 0; kk < 4; ++kk) {
        gl_lds16(pAh0 + kk * 32, dA0h);
        gl_lds16(pAl0 + kk * 32, dA0l);
        gl_lds16(pAh1 + kk * 32, dA1h);
        gl_lds16(pAl1 + kk * 32, dA1l);
        gl_lds16(pD + kk * 32, dD);
        __syncthreads();
        bf16x8 ah[4], al[4];
#pragma unroll
        for (int mf = 0; mf < 4; ++mf) {
          const int ao = (wr * 64 + mf * 16 + fm) * 32 + psw;
          ah[mf] = *(const bf16x8*)(sAh + ao);
          al[mf] = *(const bf16x8*)(sAl + ao);
        }
        const int bo = (wc * 16 + fm) * 32 + psw;
        const bf16x8 bh = *(const bf16x8*)(sBh + bo);
        const bf16x8 bl = *(const bf16x8*)(sBl + bo);
#pragma unroll
        for (int mf = 0; mf < 4; ++mf) {
          dacc[mf] = __builtin_amdgcn_mfma_f32_16x16x32_bf16(ah[mf], bh, dacc[mf], 0, 0, 0);
          dacc[mf] = __builtin_amdgcn_mfma_f32_16x16x32_bf16(ah[mf], bl, dacc[mf], 0, 0, 0);
          dacc[mf] = __builtin_amdgcn_mfma_f32_16x16x32_bf16(al[mf], bh, dacc[mf], 0, 0, 0);
        }
        __syncthreads();
      }
      pAh0 += 128; pAl0 += 128; pAh1 += 128; pAl1 += 128; pD += 128;
    }
  }

  // ---------------- phase 2: gates  acc = X @ W'^T ----------------
  f32x4 acc[4][4];
#pragma unroll
  for (int i = 0; i < 4; ++i)
#pragma unroll
    for (int j = 0; j < 4; ++j) acc[i][j] = {0.f, 0.f, 0.f, 0.f};

  {
    const long aoff = (long)(m0 + wave * 16 + srow) * 1536 + ssw;
    const long boff = (long)(n0 + wave * 16 + srow) * 1536 + ssw;
    const unsigned short* pXh0 = Xh + aoff;
    const unsigned short* pXl0 = Xl + aoff;
    const unsigned short* pXh1 = pXh0 + 64 * 1536;
    const unsigned short* pXl1 = pXl0 + 64 * 1536;
    const unsigned short* pWh0 = Wh + boff;
    const unsigned short* pWl0 = Wl + boff;
    const unsigned short* pWh1 = pWh0 + 64 * 1536;
    const unsigned short* pWl1 = pWl0 + 64 * 1536;

    for (int kt = 0; kt < 1536; kt += 128) {
#pragma unroll
      for (int kk = 0; kk < 4; ++kk) {
        gl_lds16(pXh0 + kk * 32, dA0h);
        gl_lds16(pXl0 + kk * 32, dA0l);
        gl_lds16(pXh1 + kk * 32, dA1h);
        gl_lds16(pXl1 + kk * 32, dA1l);
        gl_lds16(pWh0 + kk * 32, dB0h);
        gl_lds16(pWl0 + kk * 32, dB0l);
        gl_lds16(pWh1 + kk * 32, dB1h);
        gl_lds16(pWl1 + kk * 32, dB1l);
        __syncthreads();
        bf16x8 ah[4], al[4], bh[4], bl[4];
#pragma unroll
        for (int mf = 0; mf < 4; ++mf) {
          const int ao = (wr * 64 + mf * 16 + fm) * 32 + psw;
          ah[mf] = *(const bf16x8*)(sAh + ao);
          al[mf] = *(const bf16x8*)(sAl + ao);
        }
#pragma unroll
        for (int nf = 0; nf < 4; ++nf) {
          const int bo = (wc * 64 + nf * 16 + fm) * 32 + psw;
          bh[nf] = *(const bf16x8*)(sBh + bo);
          bl[nf] = *(const bf16x8*)(sBl + bo);
        }
#pragma unroll
        for (int nf = 0; nf < 4; ++nf)
#pragma unroll
          for (int mf = 0; mf < 4; ++mf) {
            acc[mf][nf] = __builtin_amdgcn_mfma_f32_16x16x32_bf16(ah[mf], bh[nf], acc[mf][nf], 0, 0, 0);
            acc[mf][nf] = __builtin_amdgcn_mfma_f32_16x16x32_bf16(ah[mf], bl[nf], acc[mf][nf], 0, 0, 0);
            acc[mf][nf] = __builtin_amdgcn_mfma_f32_16x16x32_bf16(al[mf], bh[nf], acc[mf][nf], 0, 0, 0);
          }
        __syncthreads();
      }
      pXh0 += 128; pXl0 += 128; pXh1 += 128; pXl1 += 128;
      pWh0 += 128; pWl0 += 128; pWh1 += 128; pWl1 += 128;
    }
  }

  // ---------------- epilogue: full T-LSTM pointwise ----------------
  // thread outputs: m = m0 + wr*64 + mf*16 + fq*4 + r ; h = h0 + wc*16 + fm
  // gate nf of acc[mf][nf][r]: 0=i 1=f 2=g 3=o
  const int h = h0 + wc * 16 + fm;
  const float bi  = b_ih[h]        + b_hh[h];
  const float bff = b_ih[1024 + h] + b_hh[1024 + h];
  const float bg  = b_ih[2048 + h] + b_hh[2048 + h];
  const float bo2 = b_ih[3072 + h] + b_hh[3072 + h];
  const float bd  = b_d[h];
#pragma unroll
  for (int mf = 0; mf < 4; ++mf) {
#pragma unroll
    for (int r = 0; r < 4; ++r) {
      const int m = m0 + wr * 64 + mf * 16 + fq * 4 + r;
      const float tv = t[m];
      const float T = (tv != 0.0f) ? (1.0f / tv) : 0.0f;
      const float cst = tanh_f(dacc[mf][r] + bd);
      const float cadj = cx[(long)m * 1024 + h] + (T - 1.0f) * cst;
      const float ig = sigm_f(acc[mf][0][r] + bi);
      const float fg = sigm_f(acc[mf][1][r] + bff);
      const float cg = tanh_f(acc[mf][2][r] + bg);
      const float og = sigm_f(acc[mf][3][r] + bo2);
      const float cyv = fg * cadj + ig * cg;
      const float hyv = og * tanh_f(cyv);
      out[(long)m * 1024 + h] = hyv;
      out[4096L * 1024 + (long)m * 1024 + h] = cyv;
    }
  }
}

extern "C" void kernel_launch(void* const* d_in, const int* in_sizes, int n_in,
                              void* d_out, int out_size, void* d_ws, size_t ws_size,
                              hipStream_t stream) {
  const float* input = (const float*)d_in[0];
  const float* t     = (const float*)d_in[1];
  const float* hx    = (const float*)d_in[2];
  const float* cx    = (const float*)d_in[3];
  const float* w_ih  = (const float*)d_in[4];
  const float* w_hh  = (const float*)d_in[5];
  const float* b_ih  = (const float*)d_in[6];
  const float* b_hh  = (const float*)d_in[7];
  const float* Wd    = (const float*)d_in[8];
  const float* b_d   = (const float*)d_in[9];

  const long B = 4096, H = 1024, KX = 1536, NG = 4096;

  char* ws = (char*)d_ws;
  unsigned short* Xhi = (unsigned short*)ws; ws += B * KX * 2;
  unsigned short* Xlo = (unsigned short*)ws; ws += B * KX * 2;
  unsigned short* Whi = (unsigned short*)ws; ws += NG * KX * 2;
  unsigned short* Wlo = (unsigned short*)ws; ws += NG * KX * 2;
  unsigned short* Chi = (unsigned short*)ws; ws += B * H * 2;
  unsigned short* Clo = (unsigned short*)ws; ws += B * H * 2;
  unsigned short* Dhi = (unsigned short*)ws; ws += H * H * 2;
  unsigned short* Dlo = (unsigned short*)ws; ws += H * H * 2;

  // 1: hi/lo splits (X+cx fused, W 16-h gate-interleaved) + W_decomp transpose
  prep_k<<<8448, 384, 0, stream>>>(input, hx, w_ih, w_hh, cx, Wd,
                                   Xhi, Xlo, Whi, Wlo, Chi, Clo, Dhi, Dlo);
  // 2: mega GEMM (decomp + gates + full pointwise epilogue)
  gemm_mega<<<1024, 256, 0, stream>>>(Xhi, Xlo, Whi, Wlo, Chi, Clo, Dhi, Dlo,
                                      b_ih, b_hh, b_d, cx, t, (float*)d_out);
}

// Round 8
// 312.817 us; speedup vs baseline: 1.1040x; 1.0291x over previous
//
#include <hip/hip_runtime.h>
#include <cstdint>

// ---------------------------------------------------------------------------
// T-LSTM cell, fp32 in/out, split-bf16 MFMA.
// Round 12: R11 + selective 2-term split in phase 2. Error analysis: output
// error is dominated by the T=1/t amplification (T up to ~4096), which flows
// only through the decomp GEMM (C_ST -> (T-1)*C_ST) and the forgetgate
// (fg * cadj). Those keep the full 3-term hi/lo split. The i/g/o gates feed
// bounded terms (ig*cg<=1, og<=1): dropping their X-lo correction (al.bh)
// adds ~0.04 abs error vs the ~8 amplified component -> negligible.
// Phase-2 MFMA/wave/step: 48 -> 36 (-25% matrix-pipe demand). Staging, LDS
// reads, swizzle, phase 1, epilogue byte-identical to R11 (verified: 0 bank
// conflicts, FETCH 201MB, natural bid order for W L2-residency, ptr-walk
// staging, fused prep).
// ---------------------------------------------------------------------------

typedef __attribute__((ext_vector_type(8))) __bf16 bf16x8;
typedef __attribute__((ext_vector_type(4))) float f32x4;

__device__ __forceinline__ unsigned short f2bf_rn(float f) {
  unsigned int u = __float_as_uint(f);
  unsigned int r = u + 0x7fffu + ((u >> 16) & 1u);
  return (unsigned short)(r >> 16);
}
__device__ __forceinline__ float bf2f(unsigned short h) {
  return __uint_as_float(((unsigned int)h) << 16);
}
__device__ __forceinline__ float sigm_f(float x) {
  return 1.0f / (1.0f + __expf(-x));
}
__device__ __forceinline__ float tanh_f(float x) {
  return 1.0f - 2.0f / (__expf(2.0f * x) + 1.0f);
}
__device__ __forceinline__ void gl_lds16(const void* g, void* l) {
  __builtin_amdgcn_global_load_lds(
      (const __attribute__((address_space(1))) void*)g,
      (__attribute__((address_space(3))) void*)l, 16, 0, 0);
}

// --- prep: split X=[input|hx] + cx (fused), W=[w_ih|w_hh] (gate-interleaved),
//           and transpose-split W_decomp, all in one dispatch.
// blocks [0,4096): X row m (384 thr x 4) AND cx row m (256 thr x 4)
// blocks [4096,8192): W source row n -> dest row (h>>4)*64+g*16+(h&15)
// blocks [8192,8448): W_decomp 64x64 transpose tiles (384 thr, stride-6 rows)
__global__ __launch_bounds__(384) void prep_k(
    const float* __restrict__ input, const float* __restrict__ hx,
    const float* __restrict__ w_ih, const float* __restrict__ w_hh,
    const float* __restrict__ cx, const float* __restrict__ Wd,
    unsigned short* __restrict__ Xhi, unsigned short* __restrict__ Xlo,
    unsigned short* __restrict__ Whi, unsigned short* __restrict__ Wlo,
    unsigned short* __restrict__ Chi, unsigned short* __restrict__ Clo,
    unsigned short* __restrict__ Dhi, unsigned short* __restrict__ Dlo) {
  const int bid = blockIdx.x;
  const int k = threadIdx.x << 2;
  if (bid >= 8192) {
    // ---- transpose-split W_decomp [1024,1024] -> D[h][kk] = Wd[kk][h]
    __shared__ float tile[64][65];
    const int tb = bid - 8192;
    const int bx = (tb & 15) * 64;
    const int by = (tb >> 4) * 64;
    const int tx = threadIdx.x & 63;
    const int ty = threadIdx.x >> 6;  // 0..5
    for (int r = ty; r < 64; r += 6)
      tile[r][tx] = Wd[(long)(by + r) * 1024 + bx + tx];
    __syncthreads();
    for (int r = ty; r < 64; r += 6) {
      float v = tile[tx][r];  // = Wd[by+tx][bx+r]
      unsigned short h = f2bf_rn(v);
      long o = (long)(bx + r) * 1024 + by + tx;
      Dhi[o] = h;
      Dlo[o] = f2bf_rn(v - bf2f(h));
    }
    return;
  }
  const float* src;
  unsigned short *hi, *lo;
  if (bid < 4096) {
    const long m = bid;
    // part 1: X = [input | hx]
    src = (k < 512) ? (input + m * 512 + k) : (hx + m * 1024 + (k - 512));
    hi = Xhi + m * 1536 + k;
    lo = Xlo + m * 1536 + k;
    {
      float4 v = *(const float4*)src;
      ushort4 hv, lv;
      hv.x = f2bf_rn(v.x); lv.x = f2bf_rn(v.x - bf2f(hv.x));
      hv.y = f2bf_rn(v.y); lv.y = f2bf_rn(v.y - bf2f(hv.y));
      hv.z = f2bf_rn(v.z); lv.z = f2bf_rn(v.z - bf2f(hv.z));
      hv.w = f2bf_rn(v.w); lv.w = f2bf_rn(v.w - bf2f(hv.w));
      *(ushort4*)hi = hv;
      *(ushort4*)lo = lv;
    }
    // part 2: cx (first 256 threads)
    if (k >= 1024) return;
    src = cx + m * 1024 + k;
    hi = Chi + m * 1024 + k;
    lo = Clo + m * 1024 + k;
  } else {
    const int n = bid - 4096;
    const int g = n >> 10;
    const int h = n & 1023;
    const long nd = ((long)(h >> 4) << 6) | (g << 4) | (h & 15);  // 16-h interleave
    src = (k < 512) ? (w_ih + (long)n * 512 + k) : (w_hh + (long)n * 1024 + (k - 512));
    hi = Whi + nd * 1536 + k;
    lo = Wlo + nd * 1536 + k;
  }
  float4 v = *(const float4*)src;
  ushort4 hv, lv;
  hv.x = f2bf_rn(v.x); lv.x = f2bf_rn(v.x - bf2f(hv.x));
  hv.y = f2bf_rn(v.y); lv.y = f2bf_rn(v.y - bf2f(hv.y));
  hv.z = f2bf_rn(v.z); lv.z = f2bf_rn(v.z - bf2f(hv.z));
  hv.w = f2bf_rn(v.w); lv.w = f2bf_rn(v.w - bf2f(hv.w));
  *(ushort4*)hi = hv;
  *(ushort4*)lo = lv;
}

// --- mega kernel: per block (m_blk, n_blk):
//   phase 1: dacc[4] = cx[128m] @ D[32h]^T  (K=1024, full 3-term split)
//   phase 2: acc[4][4] = X[128m] @ W'[128n']^T (K=1536); nf == gate
//            nf==1 (forgetgate): 3-term; nf in {0,2,3}: 2-term (drop al.bh)
//   epilogue: full T-LSTM pointwise -> hy, cy (direct to out)
// 256 thr, 4 waves 2Mx2N, wave tile 64x64 (4x4 16x16 frags).
// LDS swizzle (R3-verified, 0 conflicts): phys chunk p of row r holds logical
// chunk p^((r>>1)&3); staging lane L fetches logical (L&3)^((L>>3)&3).
__global__ __launch_bounds__(256) void gemm_mega(
    const unsigned short* __restrict__ Xh, const unsigned short* __restrict__ Xl,
    const unsigned short* __restrict__ Wh, const unsigned short* __restrict__ Wl,
    const unsigned short* __restrict__ Ch, const unsigned short* __restrict__ Cl,
    const unsigned short* __restrict__ Dh, const unsigned short* __restrict__ Dl,
    const float* __restrict__ b_ih, const float* __restrict__ b_hh,
    const float* __restrict__ b_d, const float* __restrict__ cx,
    const float* __restrict__ t, float* __restrict__ out) {
  __shared__ __align__(16) unsigned short sAh[128 * 32];
  __shared__ __align__(16) unsigned short sAl[128 * 32];
  __shared__ __align__(16) unsigned short sBh[128 * 32];
  __shared__ __align__(16) unsigned short sBl[128 * 32];

  // natural order (R4-proven): XCD x serves n_blk in {x, x+8, x+16, x+24}
  // for ALL m -> its 4 W-panels (3.1 MB) stay L2-resident the whole kernel.
  const int n_blk = blockIdx.x & 31;
  const int m_blk = blockIdx.x >> 5;
  const int m0 = m_blk * 128;
  const int n0 = n_blk * 128;  // interleaved-W row offset
  const int h0 = n_blk * 32;   // global h offset of this block

  const int tid = threadIdx.x;
  const int wave = tid >> 6;
  const int lane = tid & 63;
  const int wr = wave >> 1;   // 0..1 (M)
  const int wc = wave & 1;    // 0..1 (N)
  const int srow = lane >> 2;
  const int ssw = (((lane & 3) ^ ((lane >> 3) & 3)) << 3);  // bf16 elems
  const int fm = lane & 15;
  const int fq = lane >> 4;
  const int psw = (fq ^ ((fm >> 1) & 3)) << 3;

  // constant LDS staging destinations (per wave)
  unsigned short* const dA0h = sAh + (wave * 16) * 32;
  unsigned short* const dA0l = sAl + (wave * 16) * 32;
  unsigned short* const dA1h = sAh + (64 + wave * 16) * 32;
  unsigned short* const dA1l = sAl + (64 + wave * 16) * 32;
  unsigned short* const dB0h = sBh + (wave * 16) * 32;
  unsigned short* const dB0l = sBl + (wave * 16) * 32;
  unsigned short* const dB1h = sBh + (64 + wave * 16) * 32;
  unsigned short* const dB1l = sBl + (64 + wave * 16) * 32;

  // ---------------- phase 1: decomp  dacc = cx @ D^T ----------------
  f32x4 dacc[4];
#pragma unroll
  for (int i = 0; i < 4; ++i) dacc[i] = {0.f, 0.f, 0.f, 0.f};

  {
    const long aoff = (long)(m0 + wave * 16 + srow) * 1024 + ssw;
    const unsigned short* pAh0 = Ch + aoff;
    const unsigned short* pAl0 = Cl + aoff;
    const unsigned short* pAh1 = pAh0 + 64 * 1024;
    const unsigned short* pAl1 = pAl0 + 64 * 1024;
    const unsigned short* pD =
        ((wave & 2) ? Dl : Dh) + (long)(h0 + (wave & 1) * 16 + srow) * 1024 + ssw;
    unsigned short* const dD = ((wave & 2) ? sBl : sBh) + ((wave & 1) * 16) * 32;

    for (int kt = 0; kt < 1024; kt += 128) {
#pragma unroll
      for (int kk = 0; kk < 4; ++kk) {
        gl_lds16(pAh0 + kk * 32, dA0h);
        gl_lds16(pAl0 + kk * 32, dA0l);
        gl_lds16(pAh1 + kk * 32, dA1h);
        gl_lds16(pAl1 + kk * 32, dA1l);
        gl_lds16(pD + kk * 32, dD);
        __syncthreads();
        bf16x8 ah[4], al[4];
#pragma unroll
        for (int mf = 0; mf < 4; ++mf) {
          const int ao = (wr * 64 + mf * 16 + fm) * 32 + psw;
          ah[mf] = *(const bf16x8*)(sAh + ao);
          al[mf] = *(const bf16x8*)(sAl + ao);
        }
        const int bo = (wc * 16 + fm) * 32 + psw;
        const bf16x8 bh = *(const bf16x8*)(sBh + bo);
        const bf16x8 bl = *(const bf16x8*)(sBl + bo);
#pragma unroll
        for (int mf = 0; mf < 4; ++mf) {
          dacc[mf] = __builtin_amdgcn_mfma_f32_16x16x32_bf16(ah[mf], bh, dacc[mf], 0, 0, 0);
          dacc[mf] = __builtin_amdgcn_mfma_f32_16x16x32_bf16(ah[mf], bl, dacc[mf], 0, 0, 0);
          dacc[mf] = __builtin_amdgcn_mfma_f32_16x16x32_bf16(al[mf], bh, dacc[mf], 0, 0, 0);
        }
        __syncthreads();
      }
      pAh0 += 128; pAl0 += 128; pAh1 += 128; pAl1 += 128; pD += 128;
    }
  }

  // ---------------- phase 2: gates  acc = X @ W'^T ----------------
  f32x4 acc[4][4];
#pragma unroll
  for (int i = 0; i < 4; ++i)
#pragma unroll
    for (int j = 0; j < 4; ++j) acc[i][j] = {0.f, 0.f, 0.f, 0.f};

  {
    const long aoff = (long)(m0 + wave * 16 + srow) * 1536 + ssw;
    const long boff = (long)(n0 + wave * 16 + srow) * 1536 + ssw;
    const unsigned short* pXh0 = Xh + aoff;
    const unsigned short* pXl0 = Xl + aoff;
    const unsigned short* pXh1 = pXh0 + 64 * 1536;
    const unsigned short* pXl1 = pXl0 + 64 * 1536;
    const unsigned short* pWh0 = Wh + boff;
    const unsigned short* pWl0 = Wl + boff;
    const unsigned short* pWh1 = pWh0 + 64 * 1536;
    const unsigned short* pWl1 = pWl0 + 64 * 1536;

    for (int kt = 0; kt < 1536; kt += 128) {
#pragma unroll
      for (int kk = 0; kk < 4; ++kk) {
        gl_lds16(pXh0 + kk * 32, dA0h);
        gl_lds16(pXl0 + kk * 32, dA0l);
        gl_lds16(pXh1 + kk * 32, dA1h);
        gl_lds16(pXl1 + kk * 32, dA1l);
        gl_lds16(pWh0 + kk * 32, dB0h);
        gl_lds16(pWl0 + kk * 32, dB0l);
        gl_lds16(pWh1 + kk * 32, dB1h);
        gl_lds16(pWl1 + kk * 32, dB1l);
        __syncthreads();
        bf16x8 ah[4], al[4], bh[4], bl[4];
#pragma unroll
        for (int mf = 0; mf < 4; ++mf) {
          const int ao = (wr * 64 + mf * 16 + fm) * 32 + psw;
          ah[mf] = *(const bf16x8*)(sAh + ao);
          al[mf] = *(const bf16x8*)(sAl + ao);
        }
#pragma unroll
        for (int nf = 0; nf < 4; ++nf) {
          const int bo = (wc * 64 + nf * 16 + fm) * 32 + psw;
          bh[nf] = *(const bf16x8*)(sBh + bo);
          bl[nf] = *(const bf16x8*)(sBl + bo);
        }
#pragma unroll
        for (int nf = 0; nf < 4; ++nf)
#pragma unroll
          for (int mf = 0; mf < 4; ++mf) {
            acc[mf][nf] = __builtin_amdgcn_mfma_f32_16x16x32_bf16(ah[mf], bh[nf], acc[mf][nf], 0, 0, 0);
            acc[mf][nf] = __builtin_amdgcn_mfma_f32_16x16x32_bf16(ah[mf], bl[nf], acc[mf][nf], 0, 0, 0);
            if (nf == 1)  // forgetgate multiplies T-amplified cadj: keep X-lo term
              acc[mf][nf] = __builtin_amdgcn_mfma_f32_16x16x32_bf16(al[mf], bh[nf], acc[mf][nf], 0, 0, 0);
          }
        __syncthreads();
      }
      pXh0 += 128; pXl0 += 128; pXh1 += 128; pXl1 += 128;
      pWh0 += 128; pWl0 += 128; pWh1 += 128; pWl1 += 128;
    }
  }

  // ---------------- epilogue: full T-LSTM pointwise ----------------
  // thread outputs: m = m0 + wr*64 + mf*16 + fq*4 + r ; h = h0 + wc*16 + fm
  // gate nf of acc[mf][nf][r]: 0=i 1=f 2=g 3=o
  const int h = h0 + wc * 16 + fm;
  const float bi  = b_ih[h]        + b_hh[h];
  const float bff = b_ih[1024 + h] + b_hh[1024 + h];
  const float bg  = b_ih[2048 + h] + b_hh[2048 + h];
  const float bo2 = b_ih[3072 + h] + b_hh[3072 + h];
  const float bd  = b_d[h];
#pragma unroll
  for (int mf = 0; mf < 4; ++mf) {
#pragma unroll
    for (int r = 0; r < 4; ++r) {
      const int m = m0 + wr * 64 + mf * 16 + fq * 4 + r;
      const float tv = t[m];
      const float T = (tv != 0.0f) ? (1.0f / tv) : 0.0f;
      const float cst = tanh_f(dacc[mf][r] + bd);
      const float cadj = cx[(long)m * 1024 + h] + (T - 1.0f) * cst;
      const float ig = sigm_f(acc[mf][0][r] + bi);
      const float fg = sigm_f(acc[mf][1][r] + bff);
      const float cg = tanh_f(acc[mf][2][r] + bg);
      const float og = sigm_f(acc[mf][3][r] + bo2);
      const float cyv = fg * cadj + ig * cg;
      const float hyv = og * tanh_f(cyv);
      out[(long)m * 1024 + h] = hyv;
      out[4096L * 1024 + (long)m * 1024 + h] = cyv;
    }
  }
}

extern "C" void kernel_launch(void* const* d_in, const int* in_sizes, int n_in,
                              void* d_out, int out_size, void* d_ws, size_t ws_size,
                              hipStream_t stream) {
  const float* input = (const float*)d_in[0];
  const float* t     = (const float*)d_in[1];
  const float* hx    = (const float*)d_in[2];
  const float* cx    = (const float*)d_in[3];
  const float* w_ih  = (const float*)d_in[4];
  const float* w_hh  = (const float*)d_in[5];
  const float* b_ih  = (const float*)d_in[6];
  const float* b_hh  = (const float*)d_in[7];
  const float* Wd    = (const float*)d_in[8];
  const float* b_d   = (const float*)d_in[9];

  const long B = 4096, H = 1024, KX = 1536, NG = 4096;

  char* ws = (char*)d_ws;
  unsigned short* Xhi = (unsigned short*)ws; ws += B * KX * 2;
  unsigned short* Xlo = (unsigned short*)ws; ws += B * KX * 2;
  unsigned short* Whi = (unsigned short*)ws; ws += NG * KX * 2;
  unsigned short* Wlo = (unsigned short*)ws; ws += NG * KX * 2;
  unsigned short* Chi = (unsigned short*)ws; ws += B * H * 2;
  unsigned short* Clo = (unsigned short*)ws; ws += B * H * 2;
  unsigned short* Dhi = (unsigned short*)ws; ws += H * H * 2;
  unsigned short* Dlo = (unsigned short*)ws; ws += H * H * 2;

  // 1: hi/lo splits (X+cx fused, W 16-h gate-interleaved) + W_decomp transpose
  prep_k<<<8448, 384, 0, stream>>>(input, hx, w_ih, w_hh, cx, Wd,
                                   Xhi, Xlo, Whi, Wlo, Chi, Clo, Dhi, Dlo);
  // 2: mega GEMM (decomp + gates + full pointwise epilogue)
  gemm_mega<<<1024, 256, 0, stream>>>(Xhi, Xlo, Whi, Wlo, Chi, Clo, Dhi, Dlo,
                                      b_ih, b_hh, b_d, cx, t, (float*)d_out);
}